// Round 5
// baseline (83.650 us; speedup 1.0000x reference)
//
#include <hip/hip_runtime.h>

// CircuitLossV3 — closed-form, atomic-free partials, 2 dispatches.
//   trace contribution per (b,s): 2*m^2*((Σpa²)(Σpb²) + (Σpa·pb)²)
//   sum(gram) = Σ_b 2*(||U_b||_F² + tr(U_b U_b)),  U_b = Σ_s m_s pa_s pb_sᵀ (32×32)
// k1 (128 blk × 128 thr, 2 waves/blk): per-wave U partial + 6 scalars -> private slot
//     (also initializes the ticket used by k2's last-block combine)
// k2 (8 blk × 256 thr): per-batch reduce + gram contraction + impedance;
//     deterministic LAST block (device-scope ticket) combines 8 partials -> out

#define BB 8
#define SS 2048
#define NT 8
#define NN 32
#define FQ 256
#define NPOS (BB*SS)
#define NSLOT 256                        // one per wave of k1
#define WS_USLOT 0                       // [NSLOT][1024] floats
#define WS_SSLOT (NSLOT*1024)            // [NSLOT][8] floats (6 used)
#define WS_BATCH (WS_SSLOT + NSLOT*8)    // [BB][16] floats (11 used)
#define WS_TICKET (WS_BATCH + BB*16)     // 1 int

constexpr float LS_ = 0.1f;

__device__ __forceinline__ float softmax32(const float* __restrict__ src, int pos,
                                           int tgt, float* __restrict__ p) {
    const float4* q = reinterpret_cast<const float4*>(src) + pos * 8;
    #pragma unroll
    for (int i = 0; i < 8; i++) {
        float4 v = q[i];
        p[4*i] = v.x; p[4*i+1] = v.y; p[4*i+2] = v.z; p[4*i+3] = v.w;
    }
    float mx = p[0], sx = 0.f, pt = 0.f;
    #pragma unroll
    for (int i = 0; i < NN; i++) { mx = fmaxf(mx, p[i]); sx += p[i]; }
    #pragma unroll
    for (int i = 0; i < NN; i++) { pt = (i == tgt) ? p[i] : pt; }  // static idx only
    float es = 0.f;
    #pragma unroll
    for (int i = 0; i < NN; i++) { float e = expf(p[i] - mx); p[i] = e; es += e; }
    const float inv = 1.f / es;
    #pragma unroll
    for (int i = 0; i < NN; i++) p[i] *= inv;
    const float logZ = mx + logf(es);
    return (1.f - LS_) * (logZ - pt) + LS_ * (logZ - sx * (1.f / NN));
}

__global__ __launch_bounds__(128) void ck_main(
    const float* __restrict__ type_logits,
    const float* __restrict__ na_logits,
    const float* __restrict__ nb_logits,
    const float* __restrict__ values,
    const float* __restrict__ target_seq,
    float* __restrict__ ws)
{
    const int tid  = threadIdx.x;
    const int bid  = blockIdx.x;
    const int w    = tid >> 6;                // wave in block (0/1)
    const int lane = tid & 63;
    const int gw   = bid * 2 + w;             // global wave id = slot id [0,256)
    const int b    = gw >> 5;                 // 32 waves per batch
    const int s    = ((gw & 31) << 6) + lane; // 64 positions per wave
    const int pos  = b * SS + s;

    if (tid == 0 && bid == 0) {
        *reinterpret_cast<int*>(ws + WS_TICKET) = 0;  // k2's ticket (stream-ordered)
    }

    const float4 tg = reinterpret_cast<const float4*>(target_seq)[pos];
    const int tt = (int)tg.x;
    const int ta = (int)tg.y;
    const int tb = (int)tg.z;
    const float tv = tg.w;

    // ---- type softmax (8-way) + comp_mask ----
    float x[NT];
    {
        const float4* p = reinterpret_cast<const float4*>(type_logits) + pos * 2;
        float4 v0 = p[0], v1 = p[1];
        x[0]=v0.x; x[1]=v0.y; x[2]=v0.z; x[3]=v0.w;
        x[4]=v1.x; x[5]=v1.y; x[6]=v1.z; x[7]=v1.w;
    }
    float xmax = x[0], xs = 0.f, xt = 0.f;
    #pragma unroll
    for (int i = 0; i < NT; i++) { xmax = fmaxf(xmax, x[i]); xs += x[i]; }
    #pragma unroll
    for (int i = 0; i < NT; i++) { xt = (i == tt) ? x[i] : xt; }
    float es = 0.f, e012 = 0.f;
    #pragma unroll
    for (int i = 0; i < NT; i++) {
        float e = expf(x[i] - xmax);
        es += e;
        if (i < 3) e012 += e;
    }
    const float logZt = xmax + logf(es);
    const float lt = (1.f - LS_) * (logZt - xt) + LS_ * (logZt - xs * (1.f / NT));
    const float m = e012 / es;   // comp_mask = p[R]+p[L]+p[C]

    // ---- node softmaxes (32-way) ----
    float pa[NN], pb[NN];
    const float la = softmax32(na_logits, pos, ta, pa);
    const float lb = softmax32(nb_logits, pos, tb, pb);

    // ---- per-position scalars ----
    float Sa = 0.f, Sb = 0.f, dot = 0.f;
    #pragma unroll
    for (int i = 0; i < NN; i++) {
        Sa = fmaf(pa[i], pa[i], Sa);
        Sb = fmaf(pb[i], pb[i], Sb);
        dot = fmaf(pa[i], pb[i], dot);
    }
    const float self = m * dot;
    const float tr   = 2.f * m * m * (Sa * Sb + dot * dot);  // ||em||²
    const float dv   = values[pos] - tv;
    const float vsq  = dv * dv;

    // ---- wave-reduce 6 scalars, lane 0 stores to the wave's private slot ----
    float r0 = lt, r1 = la, r2 = lb, r3 = vsq, r4 = self, r5 = tr;
    #pragma unroll
    for (int o = 32; o > 0; o >>= 1) {
        r0 += __shfl_down(r0, o); r1 += __shfl_down(r1, o);
        r2 += __shfl_down(r2, o); r3 += __shfl_down(r3, o);
        r4 += __shfl_down(r4, o); r5 += __shfl_down(r5, o);
    }
    if (lane == 0) {
        float* sp = ws + WS_SSLOT + gw * 8;
        sp[0]=r0; sp[1]=r1; sp[2]=r2; sp[3]=r3; sp[4]=r4; sp[5]=r5;
    }

    // ---- stage m*pa and pb into this wave's LDS section (stride 9 f4) ----
    __shared__ float4 lpa[2][64][9];
    __shared__ float4 lpb[2][64][9];
    #pragma unroll
    for (int q = 0; q < 8; q++) {
        lpa[w][lane][q] = make_float4(m*pa[4*q], m*pa[4*q+1], m*pa[4*q+2], m*pa[4*q+3]);
        lpb[w][lane][q] = make_float4(pb[4*q], pb[4*q+1], pb[4*q+2], pb[4*q+3]);
    }
    __syncthreads();

    // ---- wave's U partial: 32x32 = Σ_t (m·pa_t) ⊗ pb_t, 4x4 tile/lane ----
    const int i4 = lane >> 3;
    const int j4 = lane & 7;
    float acc[4][4];
    #pragma unroll
    for (int ii = 0; ii < 4; ii++)
        #pragma unroll
        for (int jj = 0; jj < 4; jj++) acc[ii][jj] = 0.f;
    for (int t = 0; t < 64; t++) {
        float4 av = lpa[w][t][i4];
        float4 bv = lpb[w][t][j4];
        const float aa[4] = {av.x, av.y, av.z, av.w};
        const float bbv[4] = {bv.x, bv.y, bv.z, bv.w};
        #pragma unroll
        for (int ii = 0; ii < 4; ii++)
            #pragma unroll
            for (int jj = 0; jj < 4; jj++)
                acc[ii][jj] = fmaf(aa[ii], bbv[jj], acc[ii][jj]);
    }
    // plain float4 stores into the wave's private slot — NO atomics
    float4* slot = reinterpret_cast<float4*>(ws + WS_USLOT + gw * 1024);
    #pragma unroll
    for (int ii = 0; ii < 4; ii++)
        slot[((i4*4+ii)*32 + j4*4) >> 2] =
            make_float4(acc[ii][0], acc[ii][1], acc[ii][2], acc[ii][3]);
}

__device__ __forceinline__ float blk_reduce256(float v, float* lds) {
    #pragma unroll
    for (int o = 32; o > 0; o >>= 1) v += __shfl_down(v, o);
    const int tid = threadIdx.x;
    __syncthreads();
    if ((tid & 63) == 0) lds[tid >> 6] = v;
    __syncthreads();
    return lds[0] + lds[1] + lds[2] + lds[3];
}

// one block per batch; deterministic last block combines all 8 partials -> out
__global__ __launch_bounds__(256) void ck_batch(
    const float* __restrict__ pred_imp,
    const float* __restrict__ targ_imp,
    float* __restrict__ ws,
    float* __restrict__ out)
{
    const int tid = threadIdx.x;
    const int b   = blockIdx.x;
    __shared__ float Ub[1024];
    __shared__ float red[4];

    // ---- reduce the batch's 32 U slots (coalesced) ----
    float ua = 0.f, ub = 0.f, uc = 0.f, ud = 0.f;
    const float* base = ws + WS_USLOT + (size_t)b * 32 * 1024;
    for (int sl = 0; sl < 32; sl++) {
        const float* p = base + sl * 1024;
        ua += p[tid];
        ub += p[tid + 256];
        uc += p[tid + 512];
        ud += p[tid + 768];
    }
    Ub[tid]       = ua;
    Ub[tid + 256] = ub;
    Ub[tid + 512] = uc;
    Ub[tid + 768] = ud;
    __syncthreads();

    // ---- gram contraction partial: u² + u·uᵀ over this thread's 4 entries ----
    float gr = 0.f;
    #pragma unroll
    for (int r = 0; r < 4; r++) {
        const int e = tid + r * 256;
        const int i = e >> 5, j = e & 31;
        const float u  = Ub[e];
        const float ut = Ub[(j << 5) | i];
        gr = fmaf(u, u, gr);
        gr = fmaf(u, ut, gr);
    }

    // ---- impedance partials for batch b (f = tid, 256 threads = FQ) ----
    const float* pm = pred_imp + b * 2 * FQ;
    const float* tm = targ_imp + b * 2 * FQ;
    const int f = tid;
    const float p0 = pm[f], t0 = tm[f];
    const float dm = p0 - t0;
    const float dp = pm[FQ + f] - tm[FQ + f];
    float mag = dm * dm;
    float phs = dp * dp;
    float d1 = 0.f, d2 = 0.f;
    if (f < FQ - 1) {
        const float p1 = pm[f + 1], t1 = tm[f + 1];
        const float a = (p1 - p0) - (t1 - t0);
        d1 = a * a;
        if (f < FQ - 2) {
            const float p2 = pm[f + 2], t2 = tm[f + 2];
            const float c = (p2 - 2.f*p1 + p0) - (t2 - 2.f*t1 + t0);
            d2 = c * c;
        }
    }

    // ---- scalar slots of this batch (32 slots × 6) ----
    float s0=0.f, s1=0.f, s2=0.f, s3=0.f, s4=0.f, s5=0.f;
    if (tid < 32) {
        const float* sp = ws + WS_SSLOT + (b * 32 + tid) * 8;
        s0 = sp[0]; s1 = sp[1]; s2 = sp[2]; s3 = sp[3]; s4 = sp[4]; s5 = sp[5];
    }

    const float GR  = blk_reduce256(gr,  red);
    const float MAG = blk_reduce256(mag, red);
    const float PHS = blk_reduce256(phs, red);
    const float D1  = blk_reduce256(d1,  red);
    const float D2  = blk_reduce256(d2,  red);
    const float S0  = blk_reduce256(s0,  red);
    const float S1  = blk_reduce256(s1,  red);
    const float S2  = blk_reduce256(s2,  red);
    const float S3  = blk_reduce256(s3,  red);
    const float S4  = blk_reduce256(s4,  red);
    const float S5  = blk_reduce256(s5,  red);

    if (tid == 0) {
        float* o = ws + WS_BATCH + b * 16;
        o[0]=GR; o[1]=MAG; o[2]=PHS; o[3]=D1; o[4]=D2;
        o[5]=S0; o[6]=S1; o[7]=S2; o[8]=S3; o[9]=S4; o[10]=S5;

        // make this block's partial visible, then take a ticket (device scope)
        __threadfence();
        int* ticket = reinterpret_cast<int*>(ws + WS_TICKET);
        const int old = atomicAdd(ticket, 1);
        if (old == BB - 1) {
            // last block: all partials are visible (fence-before-ticket on writers)
            __threadfence();
            float GRt=0,MAGt=0,PHSt=0,D1t=0,D2t=0,T0=0,T1=0,T2=0,T3=0,T4=0,T5=0;
            #pragma unroll
            for (int k = 0; k < BB; k++) {
                const float* p = ws + WS_BATCH + k * 16;
                GRt+=p[0]; MAGt+=p[1]; PHSt+=p[2]; D1t+=p[3]; D2t+=p[4];
                T0+=p[5]; T1+=p[6]; T2+=p[7]; T3+=p[8]; T4+=p[9]; T5+=p[10];
            }
            const float invN = 1.f / (float)NPOS;
            const float type_loss = T0 * invN;
            const float na_loss   = T1 * invN;
            const float nb_loss   = T2 * invN;
            const float val_loss  = T3 * invN;
            const float self_p    = T4 * invN;
            const float trace     = T5;
            const float sum_gram  = 2.f * GRt;
            const float pair_sum  = 0.5f * (sum_gram - trace);
            const float dup   = pair_sum / ((float)BB * SS * (SS - 1) * 0.5f + 1e-8f);
            const float mag_l = MAGt / (float)(BB * FQ);
            const float d1_l  = D1t  / (float)(BB * (FQ - 1));
            const float d2_l  = D2t  / (float)(BB * (FQ - 2));
            const float ph_l  = PHSt / (float)(BB * FQ);
            const float total = 1.0f * type_loss + 1.0f * (na_loss + nb_loss)
                              + 0.5f * val_loss + 2.0f * self_p + 1.0f * dup
                              + 1.0f * mag_l + 0.5f * d1_l + 0.3f * d2_l + 0.1f * ph_l;
            out[0]=total; out[1]=type_loss; out[2]=na_loss; out[3]=nb_loss;
            out[4]=val_loss; out[5]=self_p; out[6]=dup; out[7]=mag_l;
            out[8]=d1_l; out[9]=d2_l; out[10]=ph_l;
        }
    }
}

extern "C" void kernel_launch(void* const* d_in, const int* in_sizes, int n_in,
                              void* d_out, int out_size, void* d_ws, size_t ws_size,
                              hipStream_t stream)
{
    const float* type_logits = (const float*)d_in[0];
    const float* na_logits   = (const float*)d_in[1];
    const float* nb_logits   = (const float*)d_in[2];
    const float* values      = (const float*)d_in[3];
    const float* target_seq  = (const float*)d_in[4];
    const float* pred_imp    = (const float*)d_in[5];
    const float* targ_imp    = (const float*)d_in[6];
    float* out = (float*)d_out;
    float* ws  = (float*)d_ws;

    // no memset: every ws location (incl. the ticket) is written before read
    ck_main<<<128, 128, 0, stream>>>(type_logits, na_logits, nb_logits,
                                     values, target_seq, ws);
    ck_batch<<<BB, 256, 0, stream>>>(pred_imp, targ_imp, ws, out);
}

// Round 6
// 82.031 us; speedup vs baseline: 1.0197x; 1.0197x over previous
//
#include <hip/hip_runtime.h>

// CircuitLossV3 — closed-form, atomic-free partials, 2 dispatches.
//   trace contribution per (b,s): 2*m^2*((Σpa²)(Σpb²) + (Σpa·pb)²)
//   sum(gram) = Σ_b 2*(||U_b||_F² + tr(U_b U_b)),  U_b = Σ_s m_s pa_s pb_sᵀ (32×32)
// k1 (256 blk × 64 thr, 1 wave/blk, all 256 CUs): per-wave U partial + 6 scalars
//     -> private slot; fast __expf/__logf transcendentals.
// k2 (8 blk × 256 thr): float4 slot reduce + gram contraction + impedance;
//     deterministic LAST block (device-scope ticket) combines 8 partials -> out

#define BB 8
#define SS 2048
#define NT 8
#define NN 32
#define FQ 256
#define NPOS (BB*SS)
#define NSLOT 256                        // one per block of k1
#define WS_USLOT 0                       // [NSLOT][1024] floats
#define WS_SSLOT (NSLOT*1024)            // [NSLOT][8] floats (6 used)
#define WS_BATCH (WS_SSLOT + NSLOT*8)    // [BB][16] floats (11 used)
#define WS_TICKET (WS_BATCH + BB*16)     // 1 int

constexpr float LS_ = 0.1f;

__device__ __forceinline__ float softmax32(const float* __restrict__ src, int pos,
                                           int tgt, float* __restrict__ p) {
    const float4* q = reinterpret_cast<const float4*>(src) + pos * 8;
    #pragma unroll
    for (int i = 0; i < 8; i++) {
        float4 v = q[i];
        p[4*i] = v.x; p[4*i+1] = v.y; p[4*i+2] = v.z; p[4*i+3] = v.w;
    }
    float mx = p[0], sx = 0.f, pt = 0.f;
    #pragma unroll
    for (int i = 0; i < NN; i++) { mx = fmaxf(mx, p[i]); sx += p[i]; }
    #pragma unroll
    for (int i = 0; i < NN; i++) { pt = (i == tgt) ? p[i] : pt; }  // static idx only
    float es = 0.f;
    #pragma unroll
    for (int i = 0; i < NN; i++) { float e = __expf(p[i] - mx); p[i] = e; es += e; }
    const float inv = 1.f / es;
    #pragma unroll
    for (int i = 0; i < NN; i++) p[i] *= inv;
    const float logZ = mx + __logf(es);
    return (1.f - LS_) * (logZ - pt) + LS_ * (logZ - sx * (1.f / NN));
}

__global__ __launch_bounds__(64) void ck_main(
    const float* __restrict__ type_logits,
    const float* __restrict__ na_logits,
    const float* __restrict__ nb_logits,
    const float* __restrict__ values,
    const float* __restrict__ target_seq,
    float* __restrict__ ws)
{
    const int tid = threadIdx.x;
    const int bid = blockIdx.x;               // == slot id [0,256)
    const int b   = bid >> 5;                 // 32 blocks per batch
    const int s   = ((bid & 31) << 6) + tid;  // 64 positions per block
    const int pos = b * SS + s;

    if (tid == 0 && bid == 0) {
        *reinterpret_cast<int*>(ws + WS_TICKET) = 0;  // k2's ticket (stream-ordered)
    }

    const float4 tg = reinterpret_cast<const float4*>(target_seq)[pos];
    const float vv = values[pos];
    const int tt = (int)tg.x;
    const int ta = (int)tg.y;
    const int tb = (int)tg.z;
    const float tv = tg.w;

    // ---- type softmax (8-way) + comp_mask ----
    float x[NT];
    {
        const float4* p = reinterpret_cast<const float4*>(type_logits) + pos * 2;
        float4 v0 = p[0], v1 = p[1];
        x[0]=v0.x; x[1]=v0.y; x[2]=v0.z; x[3]=v0.w;
        x[4]=v1.x; x[5]=v1.y; x[6]=v1.z; x[7]=v1.w;
    }
    float xmax = x[0], xs = 0.f, xt = 0.f;
    #pragma unroll
    for (int i = 0; i < NT; i++) { xmax = fmaxf(xmax, x[i]); xs += x[i]; }
    #pragma unroll
    for (int i = 0; i < NT; i++) { xt = (i == tt) ? x[i] : xt; }
    float es = 0.f, e012 = 0.f;
    #pragma unroll
    for (int i = 0; i < NT; i++) {
        float e = __expf(x[i] - xmax);
        es += e;
        if (i < 3) e012 += e;
    }
    const float logZt = xmax + __logf(es);
    const float lt = (1.f - LS_) * (logZt - xt) + LS_ * (logZt - xs * (1.f / NT));
    const float m = e012 / es;   // comp_mask = p[R]+p[L]+p[C]

    // ---- node softmaxes (32-way) ----
    float pa[NN], pb[NN];
    const float la = softmax32(na_logits, pos, ta, pa);
    const float lb = softmax32(nb_logits, pos, tb, pb);

    // ---- per-position scalars ----
    float Sa = 0.f, Sb = 0.f, dot = 0.f;
    #pragma unroll
    for (int i = 0; i < NN; i++) {
        Sa = fmaf(pa[i], pa[i], Sa);
        Sb = fmaf(pb[i], pb[i], Sb);
        dot = fmaf(pa[i], pb[i], dot);
    }
    const float self = m * dot;
    const float tr   = 2.f * m * m * (Sa * Sb + dot * dot);  // ||em||²
    const float dv   = vv - tv;
    const float vsq  = dv * dv;

    // ---- wave-reduce 6 scalars (block == 1 wave), store to private slot ----
    float r0 = lt, r1 = la, r2 = lb, r3 = vsq, r4 = self, r5 = tr;
    #pragma unroll
    for (int o = 32; o > 0; o >>= 1) {
        r0 += __shfl_down(r0, o); r1 += __shfl_down(r1, o);
        r2 += __shfl_down(r2, o); r3 += __shfl_down(r3, o);
        r4 += __shfl_down(r4, o); r5 += __shfl_down(r5, o);
    }
    if (tid == 0) {
        float* sp = ws + WS_SSLOT + bid * 8;
        sp[0]=r0; sp[1]=r1; sp[2]=r2; sp[3]=r3; sp[4]=r4; sp[5]=r5;
    }

    // ---- stage m*pa and pb into LDS (row stride 9 float4 = 36 floats) ----
    __shared__ float4 lpa[64][9];
    __shared__ float4 lpb[64][9];
    #pragma unroll
    for (int q = 0; q < 8; q++) {
        lpa[tid][q] = make_float4(m*pa[4*q], m*pa[4*q+1], m*pa[4*q+2], m*pa[4*q+3]);
        lpb[tid][q] = make_float4(pb[4*q], pb[4*q+1], pb[4*q+2], pb[4*q+3]);
    }
    __syncthreads();

    // ---- block's U partial: 32x32 = Σ_t (m·pa_t) ⊗ pb_t, 4x4 tile/thread ----
    const int i4 = tid >> 3;
    const int j4 = tid & 7;
    float acc[4][4];
    #pragma unroll
    for (int ii = 0; ii < 4; ii++)
        #pragma unroll
        for (int jj = 0; jj < 4; jj++) acc[ii][jj] = 0.f;
    for (int t = 0; t < 64; t++) {
        float4 av = lpa[t][i4];
        float4 bv = lpb[t][j4];
        const float aa[4] = {av.x, av.y, av.z, av.w};
        const float bbv[4] = {bv.x, bv.y, bv.z, bv.w};
        #pragma unroll
        for (int ii = 0; ii < 4; ii++)
            #pragma unroll
            for (int jj = 0; jj < 4; jj++)
                acc[ii][jj] = fmaf(aa[ii], bbv[jj], acc[ii][jj]);
    }
    // plain float4 stores into this block's private slot — NO atomics
    float4* slot = reinterpret_cast<float4*>(ws + WS_USLOT + bid * 1024);
    #pragma unroll
    for (int ii = 0; ii < 4; ii++)
        slot[((i4*4+ii)*32 + j4*4) >> 2] =
            make_float4(acc[ii][0], acc[ii][1], acc[ii][2], acc[ii][3]);
}

__device__ __forceinline__ float blk_reduce256(float v, float* lds) {
    #pragma unroll
    for (int o = 32; o > 0; o >>= 1) v += __shfl_down(v, o);
    const int tid = threadIdx.x;
    __syncthreads();
    if ((tid & 63) == 0) lds[tid >> 6] = v;
    __syncthreads();
    return lds[0] + lds[1] + lds[2] + lds[3];
}

// one block per batch; deterministic last block combines all 8 partials -> out
__global__ __launch_bounds__(256) void ck_batch(
    const float* __restrict__ pred_imp,
    const float* __restrict__ targ_imp,
    float* __restrict__ ws,
    float* __restrict__ out)
{
    const int tid = threadIdx.x;
    const int b   = blockIdx.x;
    __shared__ __align__(16) float Ub[1024];
    __shared__ float red[4];

    // ---- reduce the batch's 32 U slots, float4-vectorized (4 KB per wave-instr)
    const float4* base4 = reinterpret_cast<const float4*>(
        ws + WS_USLOT + (size_t)b * 32 * 1024);
    float4 acc = make_float4(0.f, 0.f, 0.f, 0.f);
    #pragma unroll 4
    for (int sl = 0; sl < 32; sl++) {
        float4 v = base4[sl * 256 + tid];
        acc.x += v.x; acc.y += v.y; acc.z += v.z; acc.w += v.w;
    }
    reinterpret_cast<float4*>(Ub)[tid] = acc;   // thread owns entries 4t..4t+3
    __syncthreads();

    // ---- gram contraction partial: u² + u·uᵀ over this thread's 4 entries ----
    float gr = 0.f;
    #pragma unroll
    for (int r = 0; r < 4; r++) {
        const int e = 4 * tid + r;
        const int i = e >> 5, j = e & 31;
        const float u  = Ub[e];
        const float ut = Ub[(j << 5) | i];
        gr = fmaf(u, u, gr);
        gr = fmaf(u, ut, gr);
    }

    // ---- impedance partials for batch b (f = tid, 256 threads = FQ) ----
    const float* pm = pred_imp + b * 2 * FQ;
    const float* tm = targ_imp + b * 2 * FQ;
    const int f = tid;
    const float p0 = pm[f], t0 = tm[f];
    const float dm = p0 - t0;
    const float dp = pm[FQ + f] - tm[FQ + f];
    float mag = dm * dm;
    float phs = dp * dp;
    float d1 = 0.f, d2 = 0.f;
    if (f < FQ - 1) {
        const float p1 = pm[f + 1], t1 = tm[f + 1];
        const float a = (p1 - p0) - (t1 - t0);
        d1 = a * a;
        if (f < FQ - 2) {
            const float p2 = pm[f + 2], t2 = tm[f + 2];
            const float c = (p2 - 2.f*p1 + p0) - (t2 - 2.f*t1 + t0);
            d2 = c * c;
        }
    }

    // ---- scalar slots of this batch (32 slots × 6) ----
    float s0=0.f, s1=0.f, s2=0.f, s3=0.f, s4=0.f, s5=0.f;
    if (tid < 32) {
        const float* sp = ws + WS_SSLOT + (b * 32 + tid) * 8;
        s0 = sp[0]; s1 = sp[1]; s2 = sp[2]; s3 = sp[3]; s4 = sp[4]; s5 = sp[5];
    }

    const float GR  = blk_reduce256(gr,  red);
    const float MAG = blk_reduce256(mag, red);
    const float PHS = blk_reduce256(phs, red);
    const float D1  = blk_reduce256(d1,  red);
    const float D2  = blk_reduce256(d2,  red);
    const float S0  = blk_reduce256(s0,  red);
    const float S1  = blk_reduce256(s1,  red);
    const float S2  = blk_reduce256(s2,  red);
    const float S3  = blk_reduce256(s3,  red);
    const float S4  = blk_reduce256(s4,  red);
    const float S5  = blk_reduce256(s5,  red);

    if (tid == 0) {
        float* o = ws + WS_BATCH + b * 16;
        o[0]=GR; o[1]=MAG; o[2]=PHS; o[3]=D1; o[4]=D2;
        o[5]=S0; o[6]=S1; o[7]=S2; o[8]=S3; o[9]=S4; o[10]=S5;

        // make this block's partial visible, then take a ticket (device scope)
        __threadfence();
        int* ticket = reinterpret_cast<int*>(ws + WS_TICKET);
        const int old = atomicAdd(ticket, 1);
        if (old == BB - 1) {
            // last block: all partials are visible (fence-before-ticket on writers)
            __threadfence();
            float GRt=0,MAGt=0,PHSt=0,D1t=0,D2t=0,T0=0,T1=0,T2=0,T3=0,T4=0,T5=0;
            #pragma unroll
            for (int k = 0; k < BB; k++) {
                const float* p = ws + WS_BATCH + k * 16;
                GRt+=p[0]; MAGt+=p[1]; PHSt+=p[2]; D1t+=p[3]; D2t+=p[4];
                T0+=p[5]; T1+=p[6]; T2+=p[7]; T3+=p[8]; T4+=p[9]; T5+=p[10];
            }
            const float invN = 1.f / (float)NPOS;
            const float type_loss = T0 * invN;
            const float na_loss   = T1 * invN;
            const float nb_loss   = T2 * invN;
            const float val_loss  = T3 * invN;
            const float self_p    = T4 * invN;
            const float trace     = T5;
            const float sum_gram  = 2.f * GRt;
            const float pair_sum  = 0.5f * (sum_gram - trace);
            const float dup   = pair_sum / ((float)BB * SS * (SS - 1) * 0.5f + 1e-8f);
            const float mag_l = MAGt / (float)(BB * FQ);
            const float d1_l  = D1t  / (float)(BB * (FQ - 1));
            const float d2_l  = D2t  / (float)(BB * (FQ - 2));
            const float ph_l  = PHSt / (float)(BB * FQ);
            const float total = 1.0f * type_loss + 1.0f * (na_loss + nb_loss)
                              + 0.5f * val_loss + 2.0f * self_p + 1.0f * dup
                              + 1.0f * mag_l + 0.5f * d1_l + 0.3f * d2_l + 0.1f * ph_l;
            out[0]=total; out[1]=type_loss; out[2]=na_loss; out[3]=nb_loss;
            out[4]=val_loss; out[5]=self_p; out[6]=dup; out[7]=mag_l;
            out[8]=d1_l; out[9]=d2_l; out[10]=ph_l;
        }
    }
}

extern "C" void kernel_launch(void* const* d_in, const int* in_sizes, int n_in,
                              void* d_out, int out_size, void* d_ws, size_t ws_size,
                              hipStream_t stream)
{
    const float* type_logits = (const float*)d_in[0];
    const float* na_logits   = (const float*)d_in[1];
    const float* nb_logits   = (const float*)d_in[2];
    const float* values      = (const float*)d_in[3];
    const float* target_seq  = (const float*)d_in[4];
    const float* pred_imp    = (const float*)d_in[5];
    const float* targ_imp    = (const float*)d_in[6];
    float* out = (float*)d_out;
    float* ws  = (float*)d_ws;

    // no memset: every ws location (incl. the ticket) is written before read
    ck_main<<<NSLOT, 64, 0, stream>>>(type_logits, na_logits, nb_logits,
                                      values, target_seq, ws);
    ck_batch<<<BB, 256, 0, stream>>>(pred_imp, targ_imp, ws, out);
}

// Round 7
// 79.603 us; speedup vs baseline: 1.0508x; 1.0305x over previous
//
#include <hip/hip_runtime.h>

// CircuitLossV3 — closed-form, atomic-free partials, 2 dispatches.
//   trace contribution per (b,s): 2*m^2*((Σpa²)(Σpb²) + (Σpa·pb)²)
//   sum(gram) = Σ_b 2*(||U_b||_F² + tr(U_b U_b)),  U_b = Σ_s m_s pa_s pb_sᵀ (32×32)
// k1 (64 blk × 256 thr, 4 waves/blk = 1/SIMD): per-wave U partial, block-level
//     LDS reduce -> 64 slots (256 KB total, was 1 MB); 6 scalars per wave slot.
// k2 (8 blk × 256 thr): 8-slot float4 reduce + gram contraction + impedance;
//     deterministic LAST block (device-scope ticket) combines 8 partials -> out

#define BB 8
#define SS 2048
#define NT 8
#define NN 32
#define FQ 256
#define NPOS (BB*SS)
#define NBLK1 64                         // k1 blocks (8 per batch)
#define NSLOT 64                         // U slots, one per k1 block
#define NWSLOT 256                       // scalar slots, one per k1 wave
#define WS_USLOT 0                       // [NSLOT][1024] floats
#define WS_SSLOT (NSLOT*1024)            // [NWSLOT][8] floats (6 used)
#define WS_BATCH (WS_SSLOT + NWSLOT*8)   // [BB][16] floats (11 used)
#define WS_TICKET (WS_BATCH + BB*16)     // 1 int

constexpr float LS_ = 0.1f;

__device__ __forceinline__ float softmax32(const float* __restrict__ src, int pos,
                                           int tgt, float* __restrict__ p) {
    const float4* q = reinterpret_cast<const float4*>(src) + pos * 8;
    #pragma unroll
    for (int i = 0; i < 8; i++) {
        float4 v = q[i];
        p[4*i] = v.x; p[4*i+1] = v.y; p[4*i+2] = v.z; p[4*i+3] = v.w;
    }
    float mx = p[0], sx = 0.f, pt = 0.f;
    #pragma unroll
    for (int i = 0; i < NN; i++) { mx = fmaxf(mx, p[i]); sx += p[i]; }
    #pragma unroll
    for (int i = 0; i < NN; i++) { pt = (i == tgt) ? p[i] : pt; }  // static idx only
    float es = 0.f;
    #pragma unroll
    for (int i = 0; i < NN; i++) { float e = __expf(p[i] - mx); p[i] = e; es += e; }
    const float inv = 1.f / es;
    #pragma unroll
    for (int i = 0; i < NN; i++) p[i] *= inv;
    const float logZ = mx + __logf(es);
    return (1.f - LS_) * (logZ - pt) + LS_ * (logZ - sx * (1.f / NN));
}

__global__ __launch_bounds__(256) void ck_main(
    const float* __restrict__ type_logits,
    const float* __restrict__ na_logits,
    const float* __restrict__ nb_logits,
    const float* __restrict__ values,
    const float* __restrict__ target_seq,
    float* __restrict__ ws)
{
    const int tid  = threadIdx.x;
    const int bid  = blockIdx.x;               // [0,64)
    const int w    = tid >> 6;                 // wave in block [0,4)
    const int lane = tid & 63;
    const int b    = bid >> 3;                 // 8 blocks per batch
    const int s    = ((bid & 7) << 8) + tid;   // 256 positions per block
    const int pos  = b * SS + s;
    const int gw   = bid * 4 + w;              // global wave id = scalar slot

    if (tid == 0 && bid == 0) {
        *reinterpret_cast<int*>(ws + WS_TICKET) = 0;  // k2's ticket (stream-ordered)
    }

    const float4 tg = reinterpret_cast<const float4*>(target_seq)[pos];
    const float vv = values[pos];
    const int tt = (int)tg.x;
    const int ta = (int)tg.y;
    const int tb = (int)tg.z;
    const float tv = tg.w;

    // ---- type softmax (8-way) + comp_mask ----
    float x[NT];
    {
        const float4* p = reinterpret_cast<const float4*>(type_logits) + pos * 2;
        float4 v0 = p[0], v1 = p[1];
        x[0]=v0.x; x[1]=v0.y; x[2]=v0.z; x[3]=v0.w;
        x[4]=v1.x; x[5]=v1.y; x[6]=v1.z; x[7]=v1.w;
    }
    float xmax = x[0], xs = 0.f, xt = 0.f;
    #pragma unroll
    for (int i = 0; i < NT; i++) { xmax = fmaxf(xmax, x[i]); xs += x[i]; }
    #pragma unroll
    for (int i = 0; i < NT; i++) { xt = (i == tt) ? x[i] : xt; }
    float es = 0.f, e012 = 0.f;
    #pragma unroll
    for (int i = 0; i < NT; i++) {
        float e = __expf(x[i] - xmax);
        es += e;
        if (i < 3) e012 += e;
    }
    const float logZt = xmax + __logf(es);
    const float lt = (1.f - LS_) * (logZt - xt) + LS_ * (logZt - xs * (1.f / NT));
    const float m = e012 / es;   // comp_mask = p[R]+p[L]+p[C]

    // ---- node softmaxes (32-way) ----
    float pa[NN], pb[NN];
    const float la = softmax32(na_logits, pos, ta, pa);
    const float lb = softmax32(nb_logits, pos, tb, pb);

    // ---- per-position scalars ----
    float Sa = 0.f, Sb = 0.f, dot = 0.f;
    #pragma unroll
    for (int i = 0; i < NN; i++) {
        Sa = fmaf(pa[i], pa[i], Sa);
        Sb = fmaf(pb[i], pb[i], Sb);
        dot = fmaf(pa[i], pb[i], dot);
    }
    const float self = m * dot;
    const float tr   = 2.f * m * m * (Sa * Sb + dot * dot);  // ||em||²
    const float dv   = vv - tv;
    const float vsq  = dv * dv;

    // ---- wave-reduce 6 scalars, lane 0 stores to the wave's slot ----
    float r0 = lt, r1 = la, r2 = lb, r3 = vsq, r4 = self, r5 = tr;
    #pragma unroll
    for (int o = 32; o > 0; o >>= 1) {
        r0 += __shfl_down(r0, o); r1 += __shfl_down(r1, o);
        r2 += __shfl_down(r2, o); r3 += __shfl_down(r3, o);
        r4 += __shfl_down(r4, o); r5 += __shfl_down(r5, o);
    }
    if (lane == 0) {
        float* sp = ws + WS_SSLOT + gw * 8;
        sp[0]=r0; sp[1]=r1; sp[2]=r2; sp[3]=r3; sp[4]=r4; sp[5]=r5;
    }

    // ---- stage m*pa, pb into this wave's LDS section (row stride 9 f4) ----
    __shared__ float4 lpa[4][64][9];
    __shared__ float4 lpb[4][64][9];
    #pragma unroll
    for (int q = 0; q < 8; q++) {
        lpa[w][lane][q] = make_float4(m*pa[4*q], m*pa[4*q+1], m*pa[4*q+2], m*pa[4*q+3]);
        lpb[w][lane][q] = make_float4(pb[4*q], pb[4*q+1], pb[4*q+2], pb[4*q+3]);
    }
    __syncthreads();

    // ---- wave's U partial: 32x32 = Σ_t (m·pa_t) ⊗ pb_t, 4x4 tile/lane ----
    const int i4 = lane >> 3;
    const int j4 = lane & 7;
    float acc[4][4];
    #pragma unroll
    for (int ii = 0; ii < 4; ii++)
        #pragma unroll
        for (int jj = 0; jj < 4; jj++) acc[ii][jj] = 0.f;
    for (int t = 0; t < 64; t++) {
        float4 av = lpa[w][t][i4];
        float4 bv = lpb[w][t][j4];
        const float aa[4] = {av.x, av.y, av.z, av.w};
        const float bbv[4] = {bv.x, bv.y, bv.z, bv.w};
        #pragma unroll
        for (int ii = 0; ii < 4; ii++)
            #pragma unroll
            for (int jj = 0; jj < 4; jj++)
                acc[ii][jj] = fmaf(aa[ii], bbv[jj], acc[ii][jj]);
    }

    // ---- block-level reduce of the 4 wave partials in LDS -> 1 slot/block ----
    __shared__ __align__(16) float Ured[4][1024];
    #pragma unroll
    for (int ii = 0; ii < 4; ii++)
        #pragma unroll
        for (int jj = 0; jj < 4; jj++)
            Ured[w][(i4*4+ii)*32 + (j4*4+jj)] = acc[ii][jj];
    __syncthreads();

    {
        const float4* u0 = reinterpret_cast<const float4*>(Ured[0]);
        const float4* u1 = reinterpret_cast<const float4*>(Ured[1]);
        const float4* u2 = reinterpret_cast<const float4*>(Ured[2]);
        const float4* u3 = reinterpret_cast<const float4*>(Ured[3]);
        float4 a = u0[tid], c = u1[tid], d = u2[tid], e = u3[tid];
        float4 sum = make_float4(a.x+c.x+d.x+e.x, a.y+c.y+d.y+e.y,
                                 a.z+c.z+d.z+e.z, a.w+c.w+d.w+e.w);
        reinterpret_cast<float4*>(ws + WS_USLOT + bid * 1024)[tid] = sum;
    }
}

__device__ __forceinline__ float blk_reduce256(float v, float* lds) {
    #pragma unroll
    for (int o = 32; o > 0; o >>= 1) v += __shfl_down(v, o);
    const int tid = threadIdx.x;
    __syncthreads();
    if ((tid & 63) == 0) lds[tid >> 6] = v;
    __syncthreads();
    return lds[0] + lds[1] + lds[2] + lds[3];
}

// one block per batch; deterministic last block combines all 8 partials -> out
__global__ __launch_bounds__(256) void ck_batch(
    const float* __restrict__ pred_imp,
    const float* __restrict__ targ_imp,
    float* __restrict__ ws,
    float* __restrict__ out)
{
    const int tid = threadIdx.x;
    const int b   = blockIdx.x;
    __shared__ __align__(16) float Ub[1024];
    __shared__ float red[4];

    // ---- reduce the batch's 8 U slots, float4-vectorized (32 KB total) ----
    const float4* base4 = reinterpret_cast<const float4*>(
        ws + WS_USLOT + (size_t)b * 8 * 1024);
    float4 acc = make_float4(0.f, 0.f, 0.f, 0.f);
    #pragma unroll
    for (int sl = 0; sl < 8; sl++) {
        float4 v = base4[sl * 256 + tid];
        acc.x += v.x; acc.y += v.y; acc.z += v.z; acc.w += v.w;
    }
    reinterpret_cast<float4*>(Ub)[tid] = acc;   // thread owns entries 4t..4t+3
    __syncthreads();

    // ---- gram contraction partial: u² + u·uᵀ over this thread's 4 entries ----
    float gr = 0.f;
    #pragma unroll
    for (int r = 0; r < 4; r++) {
        const int e = 4 * tid + r;
        const int i = e >> 5, j = e & 31;
        const float u  = Ub[e];
        const float ut = Ub[(j << 5) | i];
        gr = fmaf(u, u, gr);
        gr = fmaf(u, ut, gr);
    }

    // ---- impedance partials for batch b (f = tid, 256 threads = FQ) ----
    const float* pm = pred_imp + b * 2 * FQ;
    const float* tm = targ_imp + b * 2 * FQ;
    const int f = tid;
    const float p0 = pm[f], t0 = tm[f];
    const float dm = p0 - t0;
    const float dp = pm[FQ + f] - tm[FQ + f];
    float mag = dm * dm;
    float phs = dp * dp;
    float d1 = 0.f, d2 = 0.f;
    if (f < FQ - 1) {
        const float p1 = pm[f + 1], t1 = tm[f + 1];
        const float a = (p1 - p0) - (t1 - t0);
        d1 = a * a;
        if (f < FQ - 2) {
            const float p2 = pm[f + 2], t2 = tm[f + 2];
            const float c = (p2 - 2.f*p1 + p0) - (t2 - 2.f*t1 + t0);
            d2 = c * c;
        }
    }

    // ---- scalar slots of this batch (32 wave-slots × 6) ----
    float s0=0.f, s1=0.f, s2=0.f, s3=0.f, s4=0.f, s5=0.f;
    if (tid < 32) {
        const float* sp = ws + WS_SSLOT + (b * 32 + tid) * 8;
        s0 = sp[0]; s1 = sp[1]; s2 = sp[2]; s3 = sp[3]; s4 = sp[4]; s5 = sp[5];
    }

    const float GR  = blk_reduce256(gr,  red);
    const float MAG = blk_reduce256(mag, red);
    const float PHS = blk_reduce256(phs, red);
    const float D1  = blk_reduce256(d1,  red);
    const float D2  = blk_reduce256(d2,  red);
    const float S0  = blk_reduce256(s0,  red);
    const float S1  = blk_reduce256(s1,  red);
    const float S2  = blk_reduce256(s2,  red);
    const float S3  = blk_reduce256(s3,  red);
    const float S4  = blk_reduce256(s4,  red);
    const float S5  = blk_reduce256(s5,  red);

    if (tid == 0) {
        float* o = ws + WS_BATCH + b * 16;
        o[0]=GR; o[1]=MAG; o[2]=PHS; o[3]=D1; o[4]=D2;
        o[5]=S0; o[6]=S1; o[7]=S2; o[8]=S3; o[9]=S4; o[10]=S5;

        // make this block's partial visible, then take a ticket (device scope)
        __threadfence();
        int* ticket = reinterpret_cast<int*>(ws + WS_TICKET);
        const int old = atomicAdd(ticket, 1);
        if (old == BB - 1) {
            // last block: all partials visible (fence-before-ticket on writers)
            __threadfence();
            float GRt=0,MAGt=0,PHSt=0,D1t=0,D2t=0,T0=0,T1=0,T2=0,T3=0,T4=0,T5=0;
            #pragma unroll
            for (int k = 0; k < BB; k++) {
                const float* p = ws + WS_BATCH + k * 16;
                GRt+=p[0]; MAGt+=p[1]; PHSt+=p[2]; D1t+=p[3]; D2t+=p[4];
                T0+=p[5]; T1+=p[6]; T2+=p[7]; T3+=p[8]; T4+=p[9]; T5+=p[10];
            }
            const float invN = 1.f / (float)NPOS;
            const float type_loss = T0 * invN;
            const float na_loss   = T1 * invN;
            const float nb_loss   = T2 * invN;
            const float val_loss  = T3 * invN;
            const float self_p    = T4 * invN;
            const float trace     = T5;
            const float sum_gram  = 2.f * GRt;
            const float pair_sum  = 0.5f * (sum_gram - trace);
            const float dup   = pair_sum / ((float)BB * SS * (SS - 1) * 0.5f + 1e-8f);
            const float mag_l = MAGt / (float)(BB * FQ);
            const float d1_l  = D1t  / (float)(BB * (FQ - 1));
            const float d2_l  = D2t  / (float)(BB * (FQ - 2));
            const float ph_l  = PHSt / (float)(BB * FQ);
            const float total = 1.0f * type_loss + 1.0f * (na_loss + nb_loss)
                              + 0.5f * val_loss + 2.0f * self_p + 1.0f * dup
                              + 1.0f * mag_l + 0.5f * d1_l + 0.3f * d2_l + 0.1f * ph_l;
            out[0]=total; out[1]=type_loss; out[2]=na_loss; out[3]=nb_loss;
            out[4]=val_loss; out[5]=self_p; out[6]=dup; out[7]=mag_l;
            out[8]=d1_l; out[9]=d2_l; out[10]=ph_l;
        }
    }
}

extern "C" void kernel_launch(void* const* d_in, const int* in_sizes, int n_in,
                              void* d_out, int out_size, void* d_ws, size_t ws_size,
                              hipStream_t stream)
{
    const float* type_logits = (const float*)d_in[0];
    const float* na_logits   = (const float*)d_in[1];
    const float* nb_logits   = (const float*)d_in[2];
    const float* values      = (const float*)d_in[3];
    const float* target_seq  = (const float*)d_in[4];
    const float* pred_imp    = (const float*)d_in[5];
    const float* targ_imp    = (const float*)d_in[6];
    float* out = (float*)d_out;
    float* ws  = (float*)d_ws;

    // no memset: every ws location (incl. the ticket) is written before read
    ck_main<<<NBLK1, 256, 0, stream>>>(type_logits, na_logits, nb_logits,
                                       values, target_seq, ws);
    ck_batch<<<BB, 256, 0, stream>>>(pred_imp, targ_imp, ws, out);
}